// Round 10
// baseline (174.265 us; speedup 1.0000x reference)
//
#include <hip/hip_runtime.h>

#define NN 35

// packed fp32 helpers (v_pk_fma_f32)
typedef float v2f __attribute__((ext_vector_type(2)));

__device__ __forceinline__ v2f pk_fma(v2f a, v2f b, v2f c) {
#if __has_builtin(__builtin_elementwise_fma)
    return __builtin_elementwise_fma(a, b, c);
#else
    v2f d; d.x = fmaf(a.x, b.x, c.x); d.y = fmaf(a.y, b.y, c.y); return d;
#endif
}
__device__ __forceinline__ v2f pk_relu(v2f a) {
    v2f d; d.x = fmaxf(a.x, 0.f); d.y = fmaxf(a.y, 0.f); return d;
}
__device__ __forceinline__ v2f pk_splat(float s) { v2f d; d.x = s; d.y = s; return d; }
__device__ __forceinline__ v2f pk_make(float a, float b) { v2f d; d.x = a; d.y = b; return d; }

__device__ __forceinline__ void agst(float* p, float v) {
    __hip_atomic_store(p, v, __ATOMIC_RELAXED, __HIP_MEMORY_SCOPE_AGENT);
}

// ws layout (floats): part[64][35][256] = 573440  (part[(c*35+d)*256+o], write-coalesced)
//                     agg3[35*128] = 4480

// ===== Kernel A: layer1 (LDS-staged recompute) + layer2, coalesced partial out =====
// Grid (35, 64), 256 thr, 7 blocks/CU (VGPR 52, LDS 20KB -> 7x20=140KB fits).
__global__ __launch_bounds__(256, 7)
void edge12_kernel(const float* __restrict__ x,      // [35,1]
                   const float* __restrict__ ea,     // [1190,4]
                   const float* __restrict__ W1, const float* __restrict__ b1,
                   const float* __restrict__ root1, const float* __restrict__ bias1,
                   const float* __restrict__ W2, const float* __restrict__ b2,
                   const float* __restrict__ root2,
                   float* __restrict__ part,         // [64][35][256]
                   float* __restrict__ agg3)         // [35*128], zeroed here
{
    const int d  = blockIdx.x;
    const int c  = blockIdx.y;
    const int i0 = c * 8;
    const int o  = threadIdx.x;
    const int bid = c * 35 + d;

    __shared__ __align__(16) float4 eas[1190];
    __shared__ __align__(16) float hs[35][8];
    __shared__ float xs[NN];

    // zero agg3 (blocks 0..17 cover 4608 >= 4480 slots)
    if (bid < 18) {
        const int zi = bid * 256 + o;
        if (zi < 35 * 128) agst(&agg3[zi], 0.f);
    }

    // weight fragments first: global fetch overlaps ea staging
    v2f Wv0[4], Wv1[4], Wv2[4], Wv3[4], BB[4], RR[4];
#pragma unroll
    for (int p = 0; p < 4; ++p) {
        const size_t b0 = (size_t)(i0 + 2 * p) * 256 + o;
        const size_t bq = b0 + 256;
        Wv0[p] = pk_make(W2[b0],          W2[bq]);
        Wv1[p] = pk_make(W2[131072 + b0], W2[131072 + bq]);
        Wv2[p] = pk_make(W2[262144 + b0], W2[262144 + bq]);
        Wv3[p] = pk_make(W2[393216 + b0], W2[393216 + bq]);
        BB[p]  = pk_make(b2[b0],          b2[bq]);
        RR[p]  = pk_make(root2[b0],       root2[bq]);
    }

    // stage full ea (1190 float4, ~4.7/thread, coalesced) + x
    for (int e = o; e < 1190; e += 256) eas[e] = ((const float4*)ea)[e];
    if (o < NN) xs[o] = x[o];
    __syncthreads();

    // ---- inline layer 1: h1[s][i0+ii] for all s (280 values, LDS-fed) ----
    for (int e = o; e < 280; e += 256) {
        const int s = e >> 3, ii = e & 7, i = i0 + ii;
        const float w0 = W1[i], w1 = W1[512 + i], w2 = W1[1024 + i], w3 = W1[1536 + i];
        const float bb = b1[i];
        float sum = 0.f;
#pragma unroll
        for (int t = 0; t < NN; ++t) {
            if (t == s) continue;
            const float4 a = eas[t * 34 + (s < t ? s : s - 1)];
            float w = fmaf(a.x, w0, fmaf(a.y, w1, fmaf(a.z, w2, fmaf(a.w, w3, bb))));
            sum = fmaf(xs[t], fmaxf(w, 0.f), sum);
        }
        hs[s][ii] = fmaxf(sum * (1.f / 34.f) + xs[s] * root1[i] + bias1[i], 0.f);
    }
    __syncthreads();

    // ---- R6 edge2 main loop; edge row read directly from eas ----
    v2f acc0 = pk_splat(0.f), acc1 = pk_splat(0.f);
#pragma unroll 2
    for (int j = 0; j < 34; ++j) {
        const int sj = j + (j >= d ? 1 : 0);
        const float4 a = eas[sj * 34 + (d < sj ? d : d - 1)];
        const v2f ax = pk_splat(a.x), ay = pk_splat(a.y);
        const v2f az = pk_splat(a.z), aw = pk_splat(a.w);
#pragma unroll
        for (int k = 0; k < 2; ++k) {
            const float4 hv = ((const float4*)hs[sj])[k];
            {
                const int p = k * 2;
                v2f w = pk_fma(ax, Wv0[p], pk_fma(ay, Wv1[p],
                        pk_fma(az, Wv2[p], pk_fma(aw, Wv3[p], BB[p]))));
                acc0 = pk_fma(pk_make(hv.x, hv.y), pk_relu(w), acc0);
            }
            {
                const int p = k * 2 + 1;
                v2f w = pk_fma(ax, Wv0[p], pk_fma(ay, Wv1[p],
                        pk_fma(az, Wv2[p], pk_fma(aw, Wv3[p], BB[p]))));
                acc1 = pk_fma(pk_make(hv.z, hv.w), pk_relu(w), acc1);
            }
        }
    }
    v2f racc = pk_splat(0.f);
#pragma unroll
    for (int k = 0; k < 2; ++k) {
        const float4 hv = ((const float4*)hs[d])[k];
        racc = pk_fma(pk_make(hv.x, hv.y), RR[k * 2],     racc);
        racc = pk_fma(pk_make(hv.z, hv.w), RR[k * 2 + 1], racc);
    }
    const float acc = acc0.x + acc0.y + acc1.x + acc1.y;
    // coalesced disjoint partial: part[c][d][o]
    part[(size_t)bid * 256 + o] = acc * (1.f / 34.f) + (racc.x + racc.y);
}

// ===== Kernel B: layer 3 (partial-sum stage, act2 fused), 5 blocks/CU =====
// Grid (35,32) = 1120 blocks <= 256*5 -> fully co-resident in one round.
__global__ __launch_bounds__(256, 5)
void edge3_kernel(const float* __restrict__ part,   // [64][35][256]
                  const float* __restrict__ bias2,  // [256]
                  const float* __restrict__ ea,     // [1190,4]
                  const float* __restrict__ W,      // [4, 256*128]
                  const float* __restrict__ bias,   // [256*128]
                  const float* __restrict__ root,   // [256, 128]
                  float* __restrict__ agg)          // [35, 128]
{
    const int d   = blockIdx.x;
    const int c   = blockIdx.y;
    const int i0  = c * 8;
    const int thr = threadIdx.x;
    const int o   = thr & 127;
    const int g   = thr >> 7;         // i-half: 0 -> i0..i0+3, 1 -> i0+4..i0+7

    __shared__ __align__(16) float hs[35][8];
    __shared__ float4 as[34];

    // weight fragments first (overlap with staging)
    v2f Wv0[2], Wv1[2], Wv2[2], Wv3[2], BB[2], RR[2];
#pragma unroll
    for (int p = 0; p < 2; ++p) {
        const size_t b0 = (size_t)(i0 + g * 4 + 2 * p) * 128 + o;
        const size_t bq = b0 + 128;
        Wv0[p] = pk_make(W[b0],         W[bq]);
        Wv1[p] = pk_make(W[32768 + b0], W[32768 + bq]);
        Wv2[p] = pk_make(W[65536 + b0], W[65536 + bq]);
        Wv3[p] = pk_make(W[98304 + b0], W[98304 + bq]);
        BB[p]  = pk_make(bias[b0],      bias[bq]);
        RR[p]  = pk_make(root[b0],      root[bq]);
    }

    if (thr < 34) {
        const int s = thr + (thr >= d ? 1 : 0);
        as[thr] = ((const float4*)ea)[s * 34 + (d < s ? d : d - 1)];
    }

    // stage h2[s][f] = relu(sum_cc part[cc][s][f] + bias2[f])
    for (int e = thr; e < 280; e += 256) {
        const int s = e >> 3, fi = e & 7, f = i0 + fi;
        const float* pp = part + s * 256 + f;
        float s0 = 0.f, s1 = 0.f, s2 = 0.f, s3 = 0.f;
#pragma unroll
        for (int cc = 0; cc < 64; cc += 4) {
            s0 += pp[(size_t)(cc + 0) * 8960];
            s1 += pp[(size_t)(cc + 1) * 8960];
            s2 += pp[(size_t)(cc + 2) * 8960];
            s3 += pp[(size_t)(cc + 3) * 8960];
        }
        hs[s][fi] = fmaxf((s0 + s1) + (s2 + s3) + bias2[f], 0.f);
    }
    __syncthreads();

    v2f acc0 = pk_splat(0.f), acc1 = pk_splat(0.f);
#pragma unroll 2
    for (int j = 0; j < 34; ++j) {
        const int sj = j + (j >= d ? 1 : 0);
        const float4 a = as[j];
        const v2f ax = pk_splat(a.x), ay = pk_splat(a.y);
        const v2f az = pk_splat(a.z), aw = pk_splat(a.w);
        const float4 hv = ((const float4*)hs[sj])[g];
        {
            v2f w = pk_fma(ax, Wv0[0], pk_fma(ay, Wv1[0],
                    pk_fma(az, Wv2[0], pk_fma(aw, Wv3[0], BB[0]))));
            acc0 = pk_fma(pk_make(hv.x, hv.y), pk_relu(w), acc0);
        }
        {
            v2f w = pk_fma(ax, Wv0[1], pk_fma(ay, Wv1[1],
                    pk_fma(az, Wv2[1], pk_fma(aw, Wv3[1], BB[1]))));
            acc1 = pk_fma(pk_make(hv.z, hv.w), pk_relu(w), acc1);
        }
    }
    v2f racc = pk_splat(0.f);
    {
        const float4 hv = ((const float4*)hs[d])[g];
        racc = pk_fma(pk_make(hv.x, hv.y), RR[0], racc);
        racc = pk_fma(pk_make(hv.z, hv.w), RR[1], racc);
    }
    const float acc = acc0.x + acc0.y + acc1.x + acc1.y;
    atomicAdd(&agg[d * 128 + o], acc * (1.f / 34.f) + (racc.x + racc.y));
}

// ---------------- Kernel C: pairwise L1, act3 fused; one wave per pair ----------------
__global__ __launch_bounds__(256)
void cbt_kernel(const float* __restrict__ agg3,  // [35, 128] (pre-activation)
                const float* __restrict__ bias3, // [128]
                float* __restrict__ out)         // [35,35]
{
    const int wv = blockIdx.x * 4 + (threadIdx.x >> 6);
    const int lane = threadIdx.x & 63;
    if (wv >= NN * NN) return;
    const int a_ = wv / NN, i_ = wv % NN;
    float s = 0.f;
#pragma unroll
    for (int q = 0; q < 2; ++q) {
        const int f = lane + q * 64;
        const float bb = bias3[f];
        const float hi = fmaxf(agg3[i_ * 128 + f] + bb, 0.f);
        const float ha = fmaxf(agg3[a_ * 128 + f] + bb, 0.f);
        s += fabsf(hi - ha);
    }
#pragma unroll
    for (int off = 32; off > 0; off >>= 1)
        s += __shfl_xor(s, off, 64);
    if (lane == 0) out[wv] = s;
}

extern "C" void kernel_launch(void* const* d_in, const int* in_sizes, int n_in,
                              void* d_out, int out_size, void* d_ws, size_t ws_size,
                              hipStream_t stream) {
    const float* x      = (const float*)d_in[0];
    const float* ea     = (const float*)d_in[1];
    const float* mlp1_w = (const float*)d_in[3];
    const float* mlp1_b = (const float*)d_in[4];
    const float* root1  = (const float*)d_in[5];
    const float* bias1  = (const float*)d_in[6];
    const float* mlp2_w = (const float*)d_in[7];
    const float* mlp2_b = (const float*)d_in[8];
    const float* root2  = (const float*)d_in[9];
    const float* bias2  = (const float*)d_in[10];
    const float* mlp3_w = (const float*)d_in[11];
    const float* mlp3_b = (const float*)d_in[12];
    const float* root3  = (const float*)d_in[13];
    const float* bias3  = (const float*)d_in[14];
    float* out = (float*)d_out;

    float* ws   = (float*)d_ws;
    float* part = ws;                       // 64*35*256 = 573440
    float* agg3 = ws + 573440;              // 35*128 = 4480

    // A: layer1 (LDS recompute) + layer2 -> coalesced disjoint partials; zeroes agg3
    edge12_kernel<<<dim3(NN, 64), 256, 0, stream>>>(
        x, ea, mlp1_w, mlp1_b, root1, bias1, mlp2_w, mlp2_b, root2, part, agg3);
    // B: layer3 (sums 64 partials in stage, act2 fused)
    edge3_kernel<<<dim3(NN, 32), 256, 0, stream>>>(
        part, bias2, ea, mlp3_w, mlp3_b, root3, agg3);
    // C: pairwise L1, act3 fused
    cbt_kernel<<<(NN * NN + 3) / 4, 256, 0, stream>>>(agg3, bias3, out);
}

// Round 11
// 144.534 us; speedup vs baseline: 1.2057x; 1.2057x over previous
//
#include <hip/hip_runtime.h>

#define NN 35

// packed fp32 helpers (v_pk_fma_f32)
typedef float v2f __attribute__((ext_vector_type(2)));

__device__ __forceinline__ v2f pk_fma(v2f a, v2f b, v2f c) {
#if __has_builtin(__builtin_elementwise_fma)
    return __builtin_elementwise_fma(a, b, c);
#else
    v2f d; d.x = fmaf(a.x, b.x, c.x); d.y = fmaf(a.y, b.y, c.y); return d;
#endif
}
__device__ __forceinline__ v2f pk_relu(v2f a) {
    v2f d; d.x = fmaxf(a.x, 0.f); d.y = fmaxf(a.y, 0.f); return d;
}
__device__ __forceinline__ v2f pk_splat(float s) { v2f d; d.x = s; d.y = s; return d; }
__device__ __forceinline__ v2f pk_make(float a, float b) { v2f d; d.x = a; d.y = b; return d; }

__device__ __forceinline__ void agst(float* p, float v) {
    __hip_atomic_store(p, v, __ATOMIC_RELAXED, __HIP_MEMORY_SCOPE_AGENT);
}

// ws layout (floats): part[64][35][256] = 573440  (part[(c*35+d)*256+o], write-coalesced)
//                     agg3[35*128] = 4480

// ===== Kernel A: layer1 (LDS-staged recompute) + layer2, coalesced partial out =====
// Grid (35, 64), 256 thr. launch_bounds N=4: VGPR cap 256/4=64 >= natural 52 -> NO SPILLS
// (N=7 forced VGPR 36 + 67MB scratch traffic in R10 — never exceed N where 256/N < natural VGPR).
__global__ __launch_bounds__(256, 4)
void edge12_kernel(const float* __restrict__ x,      // [35,1]
                   const float* __restrict__ ea,     // [1190,4]
                   const float* __restrict__ W1, const float* __restrict__ b1,
                   const float* __restrict__ root1, const float* __restrict__ bias1,
                   const float* __restrict__ W2, const float* __restrict__ b2,
                   const float* __restrict__ root2,
                   float* __restrict__ part,         // [64][35][256]
                   float* __restrict__ agg3)         // [35*128], zeroed here
{
    const int d  = blockIdx.x;
    const int c  = blockIdx.y;
    const int i0 = c * 8;
    const int o  = threadIdx.x;
    const int bid = c * 35 + d;

    __shared__ __align__(16) float4 eas[1190];
    __shared__ __align__(16) float hs[35][8];
    __shared__ float xs[NN];

    // zero agg3 (blocks 0..17 cover 4608 >= 4480 slots)
    if (bid < 18) {
        const int zi = bid * 256 + o;
        if (zi < 35 * 128) agst(&agg3[zi], 0.f);
    }

    // weight fragments first: global fetch overlaps ea staging
    v2f Wv0[4], Wv1[4], Wv2[4], Wv3[4], BB[4], RR[4];
#pragma unroll
    for (int p = 0; p < 4; ++p) {
        const size_t b0 = (size_t)(i0 + 2 * p) * 256 + o;
        const size_t bq = b0 + 256;
        Wv0[p] = pk_make(W2[b0],          W2[bq]);
        Wv1[p] = pk_make(W2[131072 + b0], W2[131072 + bq]);
        Wv2[p] = pk_make(W2[262144 + b0], W2[262144 + bq]);
        Wv3[p] = pk_make(W2[393216 + b0], W2[393216 + bq]);
        BB[p]  = pk_make(b2[b0],          b2[bq]);
        RR[p]  = pk_make(root2[b0],       root2[bq]);
    }

    // stage full ea (1190 float4, ~4.7/thread, coalesced) + x
    for (int e = o; e < 1190; e += 256) eas[e] = ((const float4*)ea)[e];
    if (o < NN) xs[o] = x[o];
    __syncthreads();

    // ---- inline layer 1: h1[s][i0+ii] for all s (280 values, LDS-fed) ----
    for (int e = o; e < 280; e += 256) {
        const int s = e >> 3, ii = e & 7, i = i0 + ii;
        const float w0 = W1[i], w1 = W1[512 + i], w2 = W1[1024 + i], w3 = W1[1536 + i];
        const float bb = b1[i];
        float sum = 0.f;
#pragma unroll
        for (int t = 0; t < NN; ++t) {
            if (t == s) continue;
            const float4 a = eas[t * 34 + (s < t ? s : s - 1)];
            float w = fmaf(a.x, w0, fmaf(a.y, w1, fmaf(a.z, w2, fmaf(a.w, w3, bb))));
            sum = fmaf(xs[t], fmaxf(w, 0.f), sum);
        }
        hs[s][ii] = fmaxf(sum * (1.f / 34.f) + xs[s] * root1[i] + bias1[i], 0.f);
    }
    __syncthreads();

    // ---- edge2 main loop; edge row read directly from eas ----
    v2f acc0 = pk_splat(0.f), acc1 = pk_splat(0.f);
#pragma unroll 2
    for (int j = 0; j < 34; ++j) {
        const int sj = j + (j >= d ? 1 : 0);
        const float4 a = eas[sj * 34 + (d < sj ? d : d - 1)];
        const v2f ax = pk_splat(a.x), ay = pk_splat(a.y);
        const v2f az = pk_splat(a.z), aw = pk_splat(a.w);
#pragma unroll
        for (int k = 0; k < 2; ++k) {
            const float4 hv = ((const float4*)hs[sj])[k];
            {
                const int p = k * 2;
                v2f w = pk_fma(ax, Wv0[p], pk_fma(ay, Wv1[p],
                        pk_fma(az, Wv2[p], pk_fma(aw, Wv3[p], BB[p]))));
                acc0 = pk_fma(pk_make(hv.x, hv.y), pk_relu(w), acc0);
            }
            {
                const int p = k * 2 + 1;
                v2f w = pk_fma(ax, Wv0[p], pk_fma(ay, Wv1[p],
                        pk_fma(az, Wv2[p], pk_fma(aw, Wv3[p], BB[p]))));
                acc1 = pk_fma(pk_make(hv.z, hv.w), pk_relu(w), acc1);
            }
        }
    }
    v2f racc = pk_splat(0.f);
#pragma unroll
    for (int k = 0; k < 2; ++k) {
        const float4 hv = ((const float4*)hs[d])[k];
        racc = pk_fma(pk_make(hv.x, hv.y), RR[k * 2],     racc);
        racc = pk_fma(pk_make(hv.z, hv.w), RR[k * 2 + 1], racc);
    }
    const float acc = acc0.x + acc0.y + acc1.x + acc1.y;
    // coalesced disjoint partial: part[c][d][o]
    part[(size_t)bid * 256 + o] = acc * (1.f / 34.f) + (racc.x + racc.y);
}

// ===== Kernel B: layer 3 (partial-sum stage, act2 fused), N=4 (cap 64, no spill) =====
__global__ __launch_bounds__(256, 4)
void edge3_kernel(const float* __restrict__ part,   // [64][35][256]
                  const float* __restrict__ bias2,  // [256]
                  const float* __restrict__ ea,     // [1190,4]
                  const float* __restrict__ W,      // [4, 256*128]
                  const float* __restrict__ bias,   // [256*128]
                  const float* __restrict__ root,   // [256, 128]
                  float* __restrict__ agg)          // [35, 128]
{
    const int d   = blockIdx.x;
    const int c   = blockIdx.y;
    const int i0  = c * 8;
    const int thr = threadIdx.x;
    const int o   = thr & 127;
    const int g   = thr >> 7;         // i-half: 0 -> i0..i0+3, 1 -> i0+4..i0+7

    __shared__ __align__(16) float hs[35][8];
    __shared__ float4 as[34];

    // weight fragments first (overlap with staging)
    v2f Wv0[2], Wv1[2], Wv2[2], Wv3[2], BB[2], RR[2];
#pragma unroll
    for (int p = 0; p < 2; ++p) {
        const size_t b0 = (size_t)(i0 + g * 4 + 2 * p) * 128 + o;
        const size_t bq = b0 + 128;
        Wv0[p] = pk_make(W[b0],         W[bq]);
        Wv1[p] = pk_make(W[32768 + b0], W[32768 + bq]);
        Wv2[p] = pk_make(W[65536 + b0], W[65536 + bq]);
        Wv3[p] = pk_make(W[98304 + b0], W[98304 + bq]);
        BB[p]  = pk_make(bias[b0],      bias[bq]);
        RR[p]  = pk_make(root[b0],      root[bq]);
    }

    if (thr < 34) {
        const int s = thr + (thr >= d ? 1 : 0);
        as[thr] = ((const float4*)ea)[s * 34 + (d < s ? d : d - 1)];
    }

    // stage h2[s][f] = relu(sum_cc part[cc][s][f] + bias2[f])
    for (int e = thr; e < 280; e += 256) {
        const int s = e >> 3, fi = e & 7, f = i0 + fi;
        const float* pp = part + s * 256 + f;
        float s0 = 0.f, s1 = 0.f, s2 = 0.f, s3 = 0.f;
#pragma unroll
        for (int cc = 0; cc < 64; cc += 4) {
            s0 += pp[(size_t)(cc + 0) * 8960];
            s1 += pp[(size_t)(cc + 1) * 8960];
            s2 += pp[(size_t)(cc + 2) * 8960];
            s3 += pp[(size_t)(cc + 3) * 8960];
        }
        hs[s][fi] = fmaxf((s0 + s1) + (s2 + s3) + bias2[f], 0.f);
    }
    __syncthreads();

    v2f acc0 = pk_splat(0.f), acc1 = pk_splat(0.f);
#pragma unroll 2
    for (int j = 0; j < 34; ++j) {
        const int sj = j + (j >= d ? 1 : 0);
        const float4 a = as[j];
        const v2f ax = pk_splat(a.x), ay = pk_splat(a.y);
        const v2f az = pk_splat(a.z), aw = pk_splat(a.w);
        const float4 hv = ((const float4*)hs[sj])[g];
        {
            v2f w = pk_fma(ax, Wv0[0], pk_fma(ay, Wv1[0],
                    pk_fma(az, Wv2[0], pk_fma(aw, Wv3[0], BB[0]))));
            acc0 = pk_fma(pk_make(hv.x, hv.y), pk_relu(w), acc0);
        }
        {
            v2f w = pk_fma(ax, Wv0[1], pk_fma(ay, Wv1[1],
                    pk_fma(az, Wv2[1], pk_fma(aw, Wv3[1], BB[1]))));
            acc1 = pk_fma(pk_make(hv.z, hv.w), pk_relu(w), acc1);
        }
    }
    v2f racc = pk_splat(0.f);
    {
        const float4 hv = ((const float4*)hs[d])[g];
        racc = pk_fma(pk_make(hv.x, hv.y), RR[0], racc);
        racc = pk_fma(pk_make(hv.z, hv.w), RR[1], racc);
    }
    const float acc = acc0.x + acc0.y + acc1.x + acc1.y;
    atomicAdd(&agg[d * 128 + o], acc * (1.f / 34.f) + (racc.x + racc.y));
}

// ---------------- Kernel C: pairwise L1, act3 fused; one wave per pair ----------------
__global__ __launch_bounds__(256)
void cbt_kernel(const float* __restrict__ agg3,  // [35, 128] (pre-activation)
                const float* __restrict__ bias3, // [128]
                float* __restrict__ out)         // [35,35]
{
    const int wv = blockIdx.x * 4 + (threadIdx.x >> 6);
    const int lane = threadIdx.x & 63;
    if (wv >= NN * NN) return;
    const int a_ = wv / NN, i_ = wv % NN;
    float s = 0.f;
#pragma unroll
    for (int q = 0; q < 2; ++q) {
        const int f = lane + q * 64;
        const float bb = bias3[f];
        const float hi = fmaxf(agg3[i_ * 128 + f] + bb, 0.f);
        const float ha = fmaxf(agg3[a_ * 128 + f] + bb, 0.f);
        s += fabsf(hi - ha);
    }
#pragma unroll
    for (int off = 32; off > 0; off >>= 1)
        s += __shfl_xor(s, off, 64);
    if (lane == 0) out[wv] = s;
}

extern "C" void kernel_launch(void* const* d_in, const int* in_sizes, int n_in,
                              void* d_out, int out_size, void* d_ws, size_t ws_size,
                              hipStream_t stream) {
    const float* x      = (const float*)d_in[0];
    const float* ea     = (const float*)d_in[1];
    const float* mlp1_w = (const float*)d_in[3];
    const float* mlp1_b = (const float*)d_in[4];
    const float* root1  = (const float*)d_in[5];
    const float* bias1  = (const float*)d_in[6];
    const float* mlp2_w = (const float*)d_in[7];
    const float* mlp2_b = (const float*)d_in[8];
    const float* root2  = (const float*)d_in[9];
    const float* bias2  = (const float*)d_in[10];
    const float* mlp3_w = (const float*)d_in[11];
    const float* mlp3_b = (const float*)d_in[12];
    const float* root3  = (const float*)d_in[13];
    const float* bias3  = (const float*)d_in[14];
    float* out = (float*)d_out;

    float* ws   = (float*)d_ws;
    float* part = ws;                       // 64*35*256 = 573440
    float* agg3 = ws + 573440;              // 35*128 = 4480

    // A: layer1 (LDS recompute) + layer2 -> coalesced disjoint partials; zeroes agg3
    edge12_kernel<<<dim3(NN, 64), 256, 0, stream>>>(
        x, ea, mlp1_w, mlp1_b, root1, bias1, mlp2_w, mlp2_b, root2, part, agg3);
    // B: layer3 (sums 64 partials in stage, act2 fused)
    edge3_kernel<<<dim3(NN, 32), 256, 0, stream>>>(
        part, bias2, ea, mlp3_w, mlp3_b, root3, agg3);
    // C: pairwise L1, act3 fused
    cbt_kernel<<<(NN * NN + 3) / 4, 256, 0, stream>>>(agg3, bias3, out);
}

// Round 12
// 128.356 us; speedup vs baseline: 1.3577x; 1.1260x over previous
//
#include <hip/hip_runtime.h>

#define NN 35

// packed fp32 helpers (v_pk_fma_f32)
typedef float v2f __attribute__((ext_vector_type(2)));

__device__ __forceinline__ v2f pk_fma(v2f a, v2f b, v2f c) {
#if __has_builtin(__builtin_elementwise_fma)
    return __builtin_elementwise_fma(a, b, c);
#else
    v2f d; d.x = fmaf(a.x, b.x, c.x); d.y = fmaf(a.y, b.y, c.y); return d;
#endif
}
__device__ __forceinline__ v2f pk_relu(v2f a) {
    v2f d; d.x = fmaxf(a.x, 0.f); d.y = fmaxf(a.y, 0.f); return d;
}
__device__ __forceinline__ v2f pk_splat(float s) { v2f d; d.x = s; d.y = s; return d; }
__device__ __forceinline__ v2f pk_make(float a, float b) { v2f d; d.x = a; d.y = b; return d; }

// ws layout (floats): agg2[35*256]=8960 | agg3[35*128]=4480 | h1[35*512]

// ---------------- Kernel 1: layer 1 (1 -> 512) + zero agg2/agg3 ----------------
__global__ __launch_bounds__(512)
void layer1_kernel(const float* __restrict__ x,      // [35,1]
                   const float* __restrict__ ea,     // [1190,4]
                   const float* __restrict__ W1, const float* __restrict__ b1,
                   const float* __restrict__ root1, const float* __restrict__ bias1,
                   float* __restrict__ h1,           // [35,512]
                   float* __restrict__ aggz)         // agg2..agg3, 35*384 floats
{
    const int d = blockIdx.x;
    const int o = threadIdx.x;
    const int gtid = d * 512 + o;
    if (gtid < 35 * 384) aggz[gtid] = 0.f;

    const float w0 = W1[o], w1 = W1[512 + o], w2 = W1[1024 + o], w3 = W1[1536 + o];
    const float bb = b1[o];
    float sum = 0.f;
#pragma unroll
    for (int s = 0; s < NN; ++s) {
        if (s == d) continue;
        const float4 a = ((const float4*)ea)[s * 34 + (d < s ? d : d - 1)];
        float w = fmaf(a.x, w0, fmaf(a.y, w1, fmaf(a.z, w2, fmaf(a.w, w3, bb))));
        sum = fmaf(x[s], fmaxf(w, 0.f), sum);
    }
    h1[gtid] = fmaxf(sum * (1.f / 34.f) + x[d] * root1[o] + bias1[o], 0.f);
}

// -------- Kernel 2: layer 2 edge+root, IC=8, grid (35,64) — 2x wave concurrency -----
__global__ __launch_bounds__(256, 2)
void edge2_kernel(const float* __restrict__ h,     // [35, 512]
                  const float* __restrict__ ea,    // [1190,4]
                  const float* __restrict__ W,     // [4, 512*256]
                  const float* __restrict__ bias,  // [512*256]
                  const float* __restrict__ root,  // [512, 256]
                  float* __restrict__ agg)         // [35, 256]
{
    const int d  = blockIdx.x;
    const int c  = blockIdx.y;
    const int i0 = c * 8;
    const int o  = threadIdx.x;

    __shared__ __align__(16) float hs[35][8];
    __shared__ float4 as[34];

    // weight fragments first: their fetch overlaps the staging fetch below
    v2f Wv0[4], Wv1[4], Wv2[4], Wv3[4], BB[4], RR[4];
#pragma unroll
    for (int p = 0; p < 4; ++p) {
        const size_t b0 = (size_t)(i0 + 2 * p) * 256 + o;
        const size_t bq = b0 + 256;
        Wv0[p] = pk_make(W[b0],          W[bq]);
        Wv1[p] = pk_make(W[131072 + b0], W[131072 + bq]);
        Wv2[p] = pk_make(W[262144 + b0], W[262144 + bq]);
        Wv3[p] = pk_make(W[393216 + b0], W[393216 + bq]);
        BB[p]  = pk_make(bias[b0],       bias[bq]);
        RR[p]  = pk_make(root[b0],       root[bq]);
    }

    if (o < 70) {
        const int r = o >> 1, k = o & 1;
        const int s = (r < 34) ? (r + (r >= d ? 1 : 0)) : d;   // row 34 = d itself
        ((float4*)hs[r])[k] = ((const float4*)(h + (size_t)s * 512 + i0))[k];
    }
    if (o >= 70 && o < 104) {
        const int j = o - 70;
        const int s = j + (j >= d ? 1 : 0);
        as[j] = ((const float4*)ea)[s * 34 + (d < s ? d : d - 1)];
    }
    __syncthreads();

    v2f acc0 = pk_splat(0.f), acc1 = pk_splat(0.f);
#pragma unroll 2
    for (int j = 0; j < 34; ++j) {
        const float4 a = as[j];
        const v2f ax = pk_splat(a.x), ay = pk_splat(a.y);
        const v2f az = pk_splat(a.z), aw = pk_splat(a.w);
#pragma unroll
        for (int k = 0; k < 2; ++k) {
            const float4 hv = ((const float4*)hs[j])[k];
            {
                const int p = k * 2;
                v2f w = pk_fma(ax, Wv0[p], pk_fma(ay, Wv1[p],
                        pk_fma(az, Wv2[p], pk_fma(aw, Wv3[p], BB[p]))));
                acc0 = pk_fma(pk_make(hv.x, hv.y), pk_relu(w), acc0);
            }
            {
                const int p = k * 2 + 1;
                v2f w = pk_fma(ax, Wv0[p], pk_fma(ay, Wv1[p],
                        pk_fma(az, Wv2[p], pk_fma(aw, Wv3[p], BB[p]))));
                acc1 = pk_fma(pk_make(hv.z, hv.w), pk_relu(w), acc1);
            }
        }
    }
    v2f racc = pk_splat(0.f);
#pragma unroll
    for (int k = 0; k < 2; ++k) {
        const float4 hv = ((const float4*)hs[34])[k];
        racc = pk_fma(pk_make(hv.x, hv.y), RR[k * 2],     racc);
        racc = pk_fma(pk_make(hv.z, hv.w), RR[k * 2 + 1], racc);
    }
    const float acc = acc0.x + acc0.y + acc1.x + acc1.y;
    atomicAdd(&agg[d * 256 + o], acc * (1.f / 34.f) + (racc.x + racc.y));
}

// -------- Kernel 3: layer 3 edge+root, 256 thr (i-half split) — 2x concurrency ------
__global__ __launch_bounds__(256, 2)
void edge3_kernel(const float* __restrict__ agg2,  // [35, 256] (pre-activation)
                  const float* __restrict__ bias2, // [256]
                  const float* __restrict__ ea,    // [1190,4]
                  const float* __restrict__ W,     // [4, 256*128]
                  const float* __restrict__ bias,  // [256*128]
                  const float* __restrict__ root,  // [256, 128]
                  float* __restrict__ agg)         // [35, 128]
{
    const int d   = blockIdx.x;
    const int c   = blockIdx.y;
    const int i0  = c * 8;
    const int thr = threadIdx.x;
    const int o   = thr & 127;
    const int g   = thr >> 7;         // i-half: 0 -> i0..i0+3, 1 -> i0+4..i0+7

    __shared__ __align__(16) float hs[35][8];
    __shared__ float4 as[34];

    // weight fragments first (overlap with staging)
    v2f Wv0[2], Wv1[2], Wv2[2], Wv3[2], BB[2], RR[2];
#pragma unroll
    for (int p = 0; p < 2; ++p) {
        const size_t b0 = (size_t)(i0 + g * 4 + 2 * p) * 128 + o;
        const size_t bq = b0 + 128;
        Wv0[p] = pk_make(W[b0],         W[bq]);
        Wv1[p] = pk_make(W[32768 + b0], W[32768 + bq]);
        Wv2[p] = pk_make(W[65536 + b0], W[65536 + bq]);
        Wv3[p] = pk_make(W[98304 + b0], W[98304 + bq]);
        BB[p]  = pk_make(bias[b0],      bias[bq]);
        RR[p]  = pk_make(root[b0],      root[bq]);
    }

    if (thr < 70) {
        const int r = thr >> 1, k = thr & 1;
        const int s = (r < 34) ? (r + (r >= d ? 1 : 0)) : d;   // row 34 = d itself
        float4 v = ((const float4*)(agg2 + (size_t)s * 256 + i0))[k];
        const float4 bv = ((const float4*)(bias2 + i0))[k];
        v.x = fmaxf(v.x + bv.x, 0.f);
        v.y = fmaxf(v.y + bv.y, 0.f);
        v.z = fmaxf(v.z + bv.z, 0.f);
        v.w = fmaxf(v.w + bv.w, 0.f);
        ((float4*)hs[r])[k] = v;
    }
    if (thr >= 70 && thr < 104) {
        const int j = thr - 70;
        const int s = j + (j >= d ? 1 : 0);
        as[j] = ((const float4*)ea)[s * 34 + (d < s ? d : d - 1)];
    }
    __syncthreads();

    v2f acc0 = pk_splat(0.f), acc1 = pk_splat(0.f);
#pragma unroll 2
    for (int j = 0; j < 34; ++j) {
        const float4 a = as[j];
        const v2f ax = pk_splat(a.x), ay = pk_splat(a.y);
        const v2f az = pk_splat(a.z), aw = pk_splat(a.w);
        const float4 hv = ((const float4*)hs[j])[g];
        {
            v2f w = pk_fma(ax, Wv0[0], pk_fma(ay, Wv1[0],
                    pk_fma(az, Wv2[0], pk_fma(aw, Wv3[0], BB[0]))));
            acc0 = pk_fma(pk_make(hv.x, hv.y), pk_relu(w), acc0);
        }
        {
            v2f w = pk_fma(ax, Wv0[1], pk_fma(ay, Wv1[1],
                    pk_fma(az, Wv2[1], pk_fma(aw, Wv3[1], BB[1]))));
            acc1 = pk_fma(pk_make(hv.z, hv.w), pk_relu(w), acc1);
        }
    }
    v2f racc = pk_splat(0.f);
    {
        const float4 hv = ((const float4*)hs[34])[g];
        racc = pk_fma(pk_make(hv.x, hv.y), RR[0], racc);
        racc = pk_fma(pk_make(hv.z, hv.w), RR[1], racc);
    }
    const float acc = acc0.x + acc0.y + acc1.x + acc1.y;
    atomicAdd(&agg[d * 128 + o], acc * (1.f / 34.f) + (racc.x + racc.y));
}

// ---------------- Kernel 4: pairwise L1, act3 fused; one wave per pair ----------------
__global__ __launch_bounds__(256)
void cbt_kernel(const float* __restrict__ agg3,  // [35, 128] (pre-activation)
                const float* __restrict__ bias3, // [128]
                float* __restrict__ out)         // [35,35]
{
    const int wv = blockIdx.x * 4 + (threadIdx.x >> 6);
    const int lane = threadIdx.x & 63;
    if (wv >= NN * NN) return;
    const int a_ = wv / NN, i_ = wv % NN;
    float s = 0.f;
#pragma unroll
    for (int q = 0; q < 2; ++q) {
        const int f = lane + q * 64;
        const float bb = bias3[f];
        const float hi = fmaxf(agg3[i_ * 128 + f] + bb, 0.f);
        const float ha = fmaxf(agg3[a_ * 128 + f] + bb, 0.f);
        s += fabsf(hi - ha);
    }
#pragma unroll
    for (int off = 32; off > 0; off >>= 1)
        s += __shfl_xor(s, off, 64);
    if (lane == 0) out[wv] = s;
}

extern "C" void kernel_launch(void* const* d_in, const int* in_sizes, int n_in,
                              void* d_out, int out_size, void* d_ws, size_t ws_size,
                              hipStream_t stream) {
    const float* x      = (const float*)d_in[0];
    const float* ea     = (const float*)d_in[1];
    const float* mlp1_w = (const float*)d_in[3];
    const float* mlp1_b = (const float*)d_in[4];
    const float* root1  = (const float*)d_in[5];
    const float* bias1  = (const float*)d_in[6];
    const float* mlp2_w = (const float*)d_in[7];
    const float* mlp2_b = (const float*)d_in[8];
    const float* root2  = (const float*)d_in[9];
    const float* bias2  = (const float*)d_in[10];
    const float* mlp3_w = (const float*)d_in[11];
    const float* mlp3_b = (const float*)d_in[12];
    const float* root3  = (const float*)d_in[13];
    const float* bias3  = (const float*)d_in[14];
    float* out = (float*)d_out;

    float* ws   = (float*)d_ws;
    float* agg2 = ws;                  // 35*256
    float* agg3 = agg2 + 35 * 256;     // 35*128 (contiguous with agg2)
    float* h1   = agg3 + 35 * 128;     // 35*512

    // 1: layer 1 + zero aggs
    layer1_kernel<<<NN, 512, 0, stream>>>(x, ea, mlp1_w, mlp1_b, root1, bias1, h1, agg2);
    // 2: layer 2 (512 -> 256), IC=8, doubled grid for wave concurrency
    edge2_kernel<<<dim3(NN, 64), 256, 0, stream>>>(h1, ea, mlp2_w, mlp2_b, root2, agg2);
    // 3: layer 3 (256 -> 128), act2 fused, 256 threads (i-half split)
    edge3_kernel<<<dim3(NN, 32), 256, 0, stream>>>(agg2, bias2, ea, mlp3_w, mlp3_b, root3, agg3);
    // 4: pairwise L1, act3 fused (1225 waves)
    cbt_kernel<<<(NN * NN + 3) / 4, 256, 0, stream>>>(agg3, bias3, out);
}